// Round 2
// baseline (7898.708 us; speedup 1.0000x reference)
//
#include <hip/hip_runtime.h>
#include <hip/hip_cooperative_groups.h>

namespace cg = cooperative_groups;

// Grid / sim constants (match reference)
#define NXg 512
#define NYg 512
#define NTg 240
#define PITCHg 520            // padded row stride in floats (16B-aligned rows)
#define PROWSg 514            // 512 + 2 halo rows
#define BUFg (PROWSg * PITCHg)
#define NFRAMEg 60
#define FRAME_ELEMS (NXg * NYg)

// One thread per cell. 256 blocks x 1024 threads = 262144 threads.
// Block b owns rows 2b and 2b+1 (1024 = 2 * 512) -> coalesced row reads.
__global__ __launch_bounds__(1024)
void cfrp_wave_kernel(const float* __restrict__ lc11, const float* __restrict__ lc22,
                      const float* __restrict__ lc12, const float* __restrict__ lc16,
                      const float* __restrict__ lc26, const float* __restrict__ lc66,
                      const float* __restrict__ rho_p, const float* __restrict__ sig,
                      const float* __restrict__ gauss, float* __restrict__ out,
                      float* __restrict__ ws)
{
    cg::grid_group grid = cg::this_grid();

    float* uxA = ws;
    float* uxB = ws + BUFg;
    float* uyA = ws + 2 * BUFg;
    float* uyB = ws + 3 * BUFg;

    const int gtid = (int)blockIdx.x * 1024 + (int)threadIdx.x; // 0..262143
    const int i = gtid >> 9;        // row (x), 0..511
    const int j = gtid & 511;       // col (y), 0..511
    const int pb = (i + 1) * PITCHg + (j + 1);  // padded index

    // ws is re-poisoned (0xAA) before every timed call: zero all 4 buffers.
    // (Halo cells stay zero forever; interior of the "next" buffer is fully
    //  overwritten each step before being read.)
    #pragma unroll 1
    for (int k = gtid; k < 4 * BUFg; k += NXg * NYg) ws[k] = 0.0f;

    // Scalar material constants (uniform -> SGPRs)
    const float C11 = fminf(fmaxf(expf(lc11[0]), 1e9f), 1e13f);
    const float C22 = fminf(fmaxf(expf(lc22[0]), 1e9f), 1e13f);
    const float C12 = fminf(fmaxf(expf(lc12[0]), 1e9f), 1e13f);
    const float C16 = fminf(fmaxf(expf(lc16[0]), 1e9f), 1e13f);
    const float C26 = fminf(fmaxf(expf(lc26[0]), 1e9f), 1e13f);
    const float C66 = fminf(fmaxf(expf(lc66[0]), 1e9f), 1e13f);
    const float r    = rho_p[0];
    const float dt2  = 5e-8f * 5e-8f;                 // 2.5e-15
    const float hin2 = (float)(1.0 / (1e-3 * 1e-3));  // 1e6
    const float kk   = dt2 * hin2 / r;

    const float kc11   = kk * C11;
    const float kc22   = kk * C22;
    const float kc66   = kk * C66;
    const float kc16   = kk * C16;
    const float kc26   = kk * C26;
    const float kc1266 = kk * (C12 + C66);
    const float kc16x2 = 2.0f * kc16;
    const float kc26x2 = 2.0f * kc26;
    const float gf     = gauss[gtid] * (dt2 / r);     // folded force factor

    // prev-time-level displacement lives in registers (only own cell needed)
    float px = 0.0f, py = 0.0f;

    grid.sync();  // init visible to all

    const float* curx = uxA;  float* nxtx = uxB;
    const float* cury = uyA;  float* nxty = uyB;

    #pragma unroll 1
    for (int t = 0; t < NTg; ++t) {
        const float f_amp = sig[t];   // uniform scalar load

        // 9-point stencil loads, ux
        const float uxc  = curx[pb];
        const float uxn  = curx[pb - PITCHg];
        const float uxs  = curx[pb + PITCHg];
        const float uxw  = curx[pb - 1];
        const float uxe  = curx[pb + 1];
        const float uxnw = curx[pb - PITCHg - 1];
        const float uxne = curx[pb - PITCHg + 1];
        const float uxsw = curx[pb + PITCHg - 1];
        const float uxse = curx[pb + PITCHg + 1];
        // uy
        const float uyc  = cury[pb];
        const float uyn  = cury[pb - PITCHg];
        const float uys  = cury[pb + PITCHg];
        const float uyw  = cury[pb - 1];
        const float uye  = cury[pb + 1];
        const float uynw = cury[pb - PITCHg - 1];
        const float uyne = cury[pb - PITCHg + 1];
        const float uysw = cury[pb + PITCHg - 1];
        const float uyse = cury[pb + PITCHg + 1];

        // raw stencils (h^-2 folded into k-coeffs)
        const float sxx_x = uxn + uxs - 2.0f * uxc;          // d2/dx2 (rows)
        const float syy_x = uxw + uxe - 2.0f * uxc;          // d2/dy2 (cols)
        const float sxy_x = 0.25f * (uxnw - uxne - uxsw + uxse);
        const float sxx_y = uyn + uys - 2.0f * uyc;
        const float syy_y = uyw + uye - 2.0f * uyc;
        const float sxy_y = 0.25f * (uynw - uyne - uysw + uyse);

        const float lux = kc11 * sxx_x + kc66 * syy_x + kc1266 * sxy_y
                        + kc16x2 * sxy_x + kc16 * sxx_y + kc26 * syy_y;
        const float luy = kc66 * sxx_y + kc22 * syy_y + kc1266 * sxy_x
                        + kc16 * sxx_x + kc26 * syy_x + kc26x2 * sxy_y
                        + f_amp * gf;

        const float nx_ = 2.0f * uxc - px + lux;
        const float ny_ = 2.0f * uyc - py + luy;

        nxtx[pb] = nx_;
        nxty[pb] = ny_;
        px = uxc;
        py = uyc;

        if ((t & 3) == 0) {   // frames t = 0,4,...,236
            const int fo = (t >> 2) * FRAME_ELEMS + gtid;
            out[fo] = nx_;
            out[fo + NFRAMEg * FRAME_ELEMS] = ny_;
        }

        // swap ping-pong buffers
        const float* tx = curx; curx = nxtx; nxtx = (float*)tx;
        const float* ty = cury; cury = nxty; nxty = (float*)ty;

        grid.sync();  // writes of step t visible before step t+1 reads
    }
}

extern "C" void kernel_launch(void* const* d_in, const int* in_sizes, int n_in,
                              void* d_out, int out_size, void* d_ws, size_t ws_size,
                              hipStream_t stream) {
    const float* lc11  = (const float*)d_in[0];
    const float* lc22  = (const float*)d_in[1];
    const float* lc12  = (const float*)d_in[2];
    const float* lc16  = (const float*)d_in[3];
    const float* lc26  = (const float*)d_in[4];
    const float* lc66  = (const float*)d_in[5];
    const float* rho_p = (const float*)d_in[6];
    const float* sig   = (const float*)d_in[7];
    const float* gauss = (const float*)d_in[8];
    float* out = (float*)d_out;
    float* ws  = (float*)d_ws;

    void* args[] = { &lc11, &lc22, &lc12, &lc16, &lc26, &lc66,
                     &rho_p, &sig, &gauss, &out, &ws };

    dim3 grid(256), block(1024);
    hipLaunchCooperativeKernel((const void*)cfrp_wave_kernel, grid, block,
                               args, 0, stream);
}

// Round 3
// 1126.370 us; speedup vs baseline: 7.0125x; 7.0125x over previous
//
#include <hip/hip_runtime.h>

// Grid / sim constants (match reference)
#define NXg 512
#define NYg 512
#define NTg 240
#define PITCHg 520            // padded row stride in floats (16B-aligned rows)
#define PROWSg 514            // 512 + 2 halo rows
#define BUFg (PROWSg * PITCHg)
#define NFRAMEg 60
#define FRAME_ELEMS (NXg * NYg)

// Zero the 4 ping-pong field buffers (ws is re-poisoned 0xAA before every call).
__global__ __launch_bounds__(1024)
void cfrp_init(float* __restrict__ ws)
{
    const int gtid = (int)blockIdx.x * 1024 + (int)threadIdx.x; // 262144 threads
    #pragma unroll 1
    for (int k = gtid; k < 4 * BUFg; k += NXg * NYg) ws[k] = 0.0f;
}

// One timestep. cur{x,y} = u_t (read 9-pt stencil).
// oth{x,y} = holds u_{t-1} at own cell (read), overwritten with u_{t+1} (write).
// Safe in-place: no thread reads a neighbor from oth this step.
__global__ __launch_bounds__(1024)
void cfrp_step(const float* __restrict__ lc11, const float* __restrict__ lc22,
               const float* __restrict__ lc12, const float* __restrict__ lc16,
               const float* __restrict__ lc26, const float* __restrict__ lc66,
               const float* __restrict__ rho_p, const float* __restrict__ sig,
               const float* __restrict__ gauss, float* __restrict__ out,
               const float* __restrict__ curx, const float* __restrict__ cury,
               float* __restrict__ othx, float* __restrict__ othy, int t)
{
    const int gtid = (int)blockIdx.x * 1024 + (int)threadIdx.x; // 0..262143
    const int i = gtid >> 9;
    const int j = gtid & 511;
    const int pb = (i + 1) * PITCHg + (j + 1);

    // Uniform material constants (cheap; overlapped with memory latency)
    const float C11 = fminf(fmaxf(expf(lc11[0]), 1e9f), 1e13f);
    const float C22 = fminf(fmaxf(expf(lc22[0]), 1e9f), 1e13f);
    const float C12 = fminf(fmaxf(expf(lc12[0]), 1e9f), 1e13f);
    const float C16 = fminf(fmaxf(expf(lc16[0]), 1e9f), 1e13f);
    const float C26 = fminf(fmaxf(expf(lc26[0]), 1e9f), 1e13f);
    const float C66 = fminf(fmaxf(expf(lc66[0]), 1e9f), 1e13f);
    const float r    = rho_p[0];
    const float dt2  = 5e-8f * 5e-8f;                 // 2.5e-15
    const float hin2 = (float)(1.0 / (1e-3 * 1e-3));  // 1e6
    const float kk   = dt2 * hin2 / r;

    const float kc11   = kk * C11;
    const float kc22   = kk * C22;
    const float kc66   = kk * C66;
    const float kc16   = kk * C16;
    const float kc26   = kk * C26;
    const float kc1266 = kk * (C12 + C66);
    const float kc16x2 = 2.0f * kc16;
    const float kc26x2 = 2.0f * kc26;

    const float f_amp = sig[t];
    const float gf    = gauss[gtid] * (dt2 / r);

    // 9-point stencil loads, ux
    const float uxc  = curx[pb];
    const float uxn  = curx[pb - PITCHg];
    const float uxs  = curx[pb + PITCHg];
    const float uxw  = curx[pb - 1];
    const float uxe  = curx[pb + 1];
    const float uxnw = curx[pb - PITCHg - 1];
    const float uxne = curx[pb - PITCHg + 1];
    const float uxsw = curx[pb + PITCHg - 1];
    const float uxse = curx[pb + PITCHg + 1];
    // uy
    const float uyc  = cury[pb];
    const float uyn  = cury[pb - PITCHg];
    const float uys  = cury[pb + PITCHg];
    const float uyw  = cury[pb - 1];
    const float uye  = cury[pb + 1];
    const float uynw = cury[pb - PITCHg - 1];
    const float uyne = cury[pb - PITCHg + 1];
    const float uysw = cury[pb + PITCHg - 1];
    const float uyse = cury[pb + PITCHg + 1];

    const float px = othx[pb];   // u_{t-1} own cell
    const float py = othy[pb];

    const float sxx_x = uxn + uxs - 2.0f * uxc;
    const float syy_x = uxw + uxe - 2.0f * uxc;
    const float sxy_x = 0.25f * (uxnw - uxne - uxsw + uxse);
    const float sxx_y = uyn + uys - 2.0f * uyc;
    const float syy_y = uyw + uye - 2.0f * uyc;
    const float sxy_y = 0.25f * (uynw - uyne - uysw + uyse);

    const float lux = kc11 * sxx_x + kc66 * syy_x + kc1266 * sxy_y
                    + kc16x2 * sxy_x + kc16 * sxx_y + kc26 * syy_y;
    const float luy = kc66 * sxx_y + kc22 * syy_y + kc1266 * sxy_x
                    + kc16 * sxx_x + kc26 * syy_x + kc26x2 * sxy_y
                    + f_amp * gf;

    const float nx_ = 2.0f * uxc - px + lux;
    const float ny_ = 2.0f * uyc - py + luy;

    othx[pb] = nx_;   // u_{t+1} overwrites u_{t-1}
    othy[pb] = ny_;

    if ((t & 3) == 0) {   // frames t = 0,4,...,236
        const int fo = (t >> 2) * FRAME_ELEMS + gtid;
        out[fo] = nx_;
        out[fo + NFRAMEg * FRAME_ELEMS] = ny_;
    }
}

extern "C" void kernel_launch(void* const* d_in, const int* in_sizes, int n_in,
                              void* d_out, int out_size, void* d_ws, size_t ws_size,
                              hipStream_t stream) {
    const float* lc11  = (const float*)d_in[0];
    const float* lc22  = (const float*)d_in[1];
    const float* lc12  = (const float*)d_in[2];
    const float* lc16  = (const float*)d_in[3];
    const float* lc26  = (const float*)d_in[4];
    const float* lc66  = (const float*)d_in[5];
    const float* rho_p = (const float*)d_in[6];
    const float* sig   = (const float*)d_in[7];
    const float* gauss = (const float*)d_in[8];
    float* out = (float*)d_out;
    float* ws  = (float*)d_ws;

    float* uxA = ws;
    float* uxB = ws + BUFg;
    float* uyA = ws + 2 * BUFg;
    float* uyB = ws + 3 * BUFg;

    hipLaunchKernelGGL(cfrp_init, dim3(256), dim3(1024), 0, stream, ws);

    for (int t = 0; t < NTg; ++t) {
        const float *cx, *cy;
        float *ox, *oy;
        if (t & 1) { cx = uxB; cy = uyB; ox = uxA; oy = uyA; }
        else       { cx = uxA; cy = uyA; ox = uxB; oy = uyB; }
        hipLaunchKernelGGL(cfrp_step, dim3(256), dim3(1024), 0, stream,
                           lc11, lc22, lc12, lc16, lc26, lc66, rho_p, sig,
                           gauss, out, cx, cy, ox, oy, t);
    }
}

// Round 4
// 715.761 us; speedup vs baseline: 11.0354x; 1.5737x over previous
//
#include <hip/hip_runtime.h>

// ---- problem constants ----
#define NXg    512
#define Sg     262144          // 512*512
#define NTg    240
#define NFRg   60
// ---- temporal blocking ----
#define Kg     8               // steps per chunk
#define NCHUNK 30              // 240 / 8
#define TILEg  32              // owned tile (16x16 blocks)
#define Eg     48              // TILEg + 2*Kg extended tile
#define ROWCg  46              // compute region width (rows/cols 1..46)
#define CELg   (ROWCg*ROWCg)   // 2116 compute cells
#define NTHRg  512
#define NSLOTg 5               // ceil(2116/512)

// Zero the 8 global field buffers (ws re-poisoned 0xAA before every call).
__global__ __launch_bounds__(NTHRg)
void cfrp_init(float* __restrict__ ws)
{
    const int gt = (int)blockIdx.x * NTHRg + (int)threadIdx.x;
    const int stride = (int)gridDim.x * NTHRg;
    #pragma unroll 1
    for (int k = gt; k < 8 * Sg; k += stride) ws[k] = 0.0f;
}

// Advance 8 timesteps. Interleaved LDS: cell (r,c) -> sf[2*(r*Eg+c)] = ux,
// sf[2*(r*Eg+c)+1] = uy  => every 9-pt stencil tap is one ds_read_b64.
// u_{t-1} lives in per-slot registers (own-cell access only).
__global__ __launch_bounds__(NTHRg)
void cfrp_chunk(const float* __restrict__ lc11, const float* __restrict__ lc22,
                const float* __restrict__ lc12, const float* __restrict__ lc16,
                const float* __restrict__ lc26, const float* __restrict__ lc66,
                const float* __restrict__ rho_p, const float* __restrict__ sig,
                const float* __restrict__ gauss, float* __restrict__ out,
                const float* __restrict__ gcx, const float* __restrict__ gcy,
                const float* __restrict__ gpx, const float* __restrict__ gpy,
                float* __restrict__ ncx, float* __restrict__ ncy,
                float* __restrict__ npx, float* __restrict__ npy,
                int T0)
{
    __shared__ float sf[Eg * Eg * 2];

    const int tid = (int)threadIdx.x;
    const int bi = (int)blockIdx.x >> 4;
    const int bj = (int)blockIdx.x & 15;
    const int oi = bi * TILEg - Kg;       // global coords of extended tile origin
    const int oj = bj * TILEg - Kg;

    // uniform material constants
    const float C11 = fminf(fmaxf(expf(lc11[0]), 1e9f), 1e13f);
    const float C22 = fminf(fmaxf(expf(lc22[0]), 1e9f), 1e13f);
    const float C12 = fminf(fmaxf(expf(lc12[0]), 1e9f), 1e13f);
    const float C16 = fminf(fmaxf(expf(lc16[0]), 1e9f), 1e13f);
    const float C26 = fminf(fmaxf(expf(lc26[0]), 1e9f), 1e13f);
    const float C66 = fminf(fmaxf(expf(lc66[0]), 1e9f), 1e13f);
    const float r    = rho_p[0];
    const float dt2  = 2.5e-15f;          // (5e-8)^2
    const float kk   = dt2 * 1e6f / r;    // dt2 * h^-2 / rho
    const float kc11 = kk * C11, kc22 = kk * C22, kc66 = kk * C66;
    const float kc16 = kk * C16, kc26 = kk * C26;
    const float kc1266 = kk * (C12 + C66);
    const float kc16x2 = 2.0f * kc16;
    const float kc26x2 = 2.0f * kc26;
    const float gsc = dt2 / r;            // force factor

    // stage u_t (both components, interleaved) into LDS
    #pragma unroll 1
    for (int idx = tid; idx < Eg * Eg; idx += NTHRg) {
        const int rr = idx / Eg;
        const int cc = idx - rr * Eg;
        const int gi = oi + rr, gj = oj + cc;
        const bool inb = ((unsigned)gi < NXg) && ((unsigned)gj < NXg);
        const int go = gi * NXg + gj;
        sf[2 * idx]     = inb ? gcx[go] : 0.0f;
        sf[2 * idx + 1] = inb ? gcy[go] : 0.0f;
    }

    // per-slot setup (all arrays unrolled -> registers)
    int   la[NSLOTg], go[NSLOTg];
    float pvx[NSLOTg], pvy[NSLOTg], gfv[NSLOTg];
    bool  act[NSLOTg], inb[NSLOTg], own[NSLOTg];
    #pragma unroll
    for (int s = 0; s < NSLOTg; ++s) {
        const int idx = tid + s * NTHRg;
        act[s] = idx < CELg;
        const int ii = act[s] ? idx : 0;
        const int rr = ii / ROWCg + 1;            // 1..46
        const int cc = ii - (rr - 1) * ROWCg + 1; // 1..46
        la[s] = (rr * Eg + cc) * 2;
        const int gi = oi + rr, gj = oj + cc;
        inb[s] = ((unsigned)gi < NXg) && ((unsigned)gj < NXg);
        go[s] = gi * NXg + gj;
        own[s] = act[s] && rr >= Kg && rr < Kg + TILEg
                        && cc >= Kg && cc < Kg + TILEg;
        const bool ld = act[s] && inb[s];
        pvx[s] = ld ? gpx[go[s]] : 0.0f;
        pvy[s] = ld ? gpy[go[s]] : 0.0f;
        gfv[s] = ld ? gauss[go[s]] * gsc : 0.0f;
    }
    __syncthreads();

    #pragma unroll
    for (int st = 0; st < Kg; ++st) {
        const float fa = sig[T0 + st];
        float nx[NSLOTg], ny[NSLOTg];
        #pragma unroll
        for (int s = 0; s < NSLOTg; ++s) {
            const int a = la[s];
            const float2 Cc = *(const float2*)&sf[a];
            const float2 Nn = *(const float2*)&sf[a - 2 * Eg];
            const float2 Ss = *(const float2*)&sf[a + 2 * Eg];
            const float2 Ww = *(const float2*)&sf[a - 2];
            const float2 Ee = *(const float2*)&sf[a + 2];
            const float2 NW = *(const float2*)&sf[a - 2 * Eg - 2];
            const float2 NE = *(const float2*)&sf[a - 2 * Eg + 2];
            const float2 SW = *(const float2*)&sf[a + 2 * Eg - 2];
            const float2 SE = *(const float2*)&sf[a + 2 * Eg + 2];

            const float sxx_x = Nn.x + Ss.x - 2.0f * Cc.x;
            const float syy_x = Ww.x + Ee.x - 2.0f * Cc.x;
            const float sxy_x = 0.25f * (NW.x - NE.x - SW.x + SE.x);
            const float sxx_y = Nn.y + Ss.y - 2.0f * Cc.y;
            const float syy_y = Ww.y + Ee.y - 2.0f * Cc.y;
            const float sxy_y = 0.25f * (NW.y - NE.y - SW.y + SE.y);

            const float lux = kc11 * sxx_x + kc66 * syy_x + kc1266 * sxy_y
                            + kc16x2 * sxy_x + kc16 * sxx_y + kc26 * syy_y;
            const float luy = kc66 * sxx_y + kc22 * syy_y + kc1266 * sxy_x
                            + kc16 * sxx_x + kc26 * syy_x + kc26x2 * sxy_y
                            + fa * gfv[s];

            float vx = 2.0f * Cc.x - pvx[s] + lux;
            float vy = 2.0f * Cc.y - pvy[s] + luy;
            vx = inb[s] ? vx : 0.0f;   // out-of-domain cells stay 0 (zero padding)
            vy = inb[s] ? vy : 0.0f;
            pvx[s] = Cc.x;
            pvy[s] = Cc.y;
            nx[s] = vx;
            ny[s] = vy;

            if ((st & 3) == 0) {       // compile-time: frames at st = 0, 4
                if (own[s]) {
                    const int fo = ((T0 + st) >> 2) * Sg + go[s];
                    out[fo] = vx;
                    out[fo + NFRg * Sg] = vy;
                }
            }
        }
        __syncthreads();
        #pragma unroll
        for (int s = 0; s < NSLOTg; ++s) {
            if (act[s]) {
                sf[la[s]]     = nx[s];
                sf[la[s] + 1] = ny[s];
            }
        }
        __syncthreads();
    }

    // hand off state: owned cells only (each cell owned by exactly one block)
    #pragma unroll
    for (int s = 0; s < NSLOTg; ++s) {
        if (own[s]) {
            ncx[go[s]] = sf[la[s]];
            ncy[go[s]] = sf[la[s] + 1];
            npx[go[s]] = pvx[s];
            npy[go[s]] = pvy[s];
        }
    }
}

extern "C" void kernel_launch(void* const* d_in, const int* in_sizes, int n_in,
                              void* d_out, int out_size, void* d_ws, size_t ws_size,
                              hipStream_t stream) {
    const float* lc11  = (const float*)d_in[0];
    const float* lc22  = (const float*)d_in[1];
    const float* lc12  = (const float*)d_in[2];
    const float* lc16  = (const float*)d_in[3];
    const float* lc26  = (const float*)d_in[4];
    const float* lc66  = (const float*)d_in[5];
    const float* rho_p = (const float*)d_in[6];
    const float* sig   = (const float*)d_in[7];
    const float* gauss = (const float*)d_in[8];
    float* out = (float*)d_out;
    float* ws  = (float*)d_ws;

    // 8 field buffers: set A = [cx, cy, px, py], set B likewise
    float* A[4] = { ws,          ws + Sg,     ws + 2 * Sg, ws + 3 * Sg };
    float* B[4] = { ws + 4 * Sg, ws + 5 * Sg, ws + 6 * Sg, ws + 7 * Sg };

    hipLaunchKernelGGL(cfrp_init, dim3(256), dim3(NTHRg), 0, stream, ws);

    for (int c = 0; c < NCHUNK; ++c) {
        float** R = (c & 1) ? B : A;   // read set
        float** W = (c & 1) ? A : B;   // write set
        hipLaunchKernelGGL(cfrp_chunk, dim3(256), dim3(NTHRg), 0, stream,
                           lc11, lc22, lc12, lc16, lc26, lc66, rho_p, sig,
                           gauss, out,
                           R[0], R[1], R[2], R[3],
                           W[0], W[1], W[2], W[3],
                           c * Kg);
    }
}

// Round 5
// 674.254 us; speedup vs baseline: 11.7147x; 1.0616x over previous
//
#include <hip/hip_runtime.h>

// ---- problem constants ----
#define NXg    512
#define Sg     262144          // 512*512
#define NFRg   60
// ---- temporal blocking ----
#define Kg     8               // steps per chunk
#define NCHUNK 30              // 240 / 8
#define TIg    32              // owned tile rows
#define TJg    16              // owned tile cols
#define EIg    48              // extended rows  (TI + 2K)
#define EJg    32              // extended cols  (TJ + 2K)  -> shift math
#define RCIg   46              // compute rows 1..46
#define RCJg   30              // compute cols 1..30
#define CELg   (RCIg*RCJg)     // 1380
#define NTHRg  512
#define NSLOTg 3               // ceil(1380/512)

// Zero the 4 "A-set" field buffers (ws re-poisoned 0xAA before every call).
// Chunk 0 reads A and fully overwrites B's owned cells, so B needs no init.
__global__ __launch_bounds__(NTHRg)
void cfrp_init(float* __restrict__ ws)
{
    const int gt = (int)blockIdx.x * NTHRg + (int)threadIdx.x; // 262144 threads
    ((float4*)ws)[gt] = make_float4(0.f, 0.f, 0.f, 0.f);       // 4*Sg floats
}

// Advance 8 timesteps. Interleaved LDS (cell -> {ux,uy} float2), double-
// buffered: one __syncthreads per step. Center value and u_{t-1} stay in
// registers.
__global__ __launch_bounds__(NTHRg, 4)
void cfrp_chunk(const float* __restrict__ lc11, const float* __restrict__ lc22,
                const float* __restrict__ lc12, const float* __restrict__ lc16,
                const float* __restrict__ lc26, const float* __restrict__ lc66,
                const float* __restrict__ rho_p, const float* __restrict__ sig,
                const float* __restrict__ gauss, float* __restrict__ out,
                const float* __restrict__ gcx, const float* __restrict__ gcy,
                const float* __restrict__ gpx, const float* __restrict__ gpy,
                float* __restrict__ ncx, float* __restrict__ ncy,
                float* __restrict__ npx, float* __restrict__ npy,
                int T0)
{
    __shared__ float sf[2][EIg * EJg * 2];

    const int tid = (int)threadIdx.x;
    const int bi = (int)blockIdx.x >> 5;   // 0..15
    const int bj = (int)blockIdx.x & 31;   // 0..31
    const int oi = bi * TIg - Kg;
    const int oj = bj * TJg - Kg;

    // uniform material constants
    const float C11 = fminf(fmaxf(expf(lc11[0]), 1e9f), 1e13f);
    const float C22 = fminf(fmaxf(expf(lc22[0]), 1e9f), 1e13f);
    const float C12 = fminf(fmaxf(expf(lc12[0]), 1e9f), 1e13f);
    const float C16 = fminf(fmaxf(expf(lc16[0]), 1e9f), 1e13f);
    const float C26 = fminf(fmaxf(expf(lc26[0]), 1e9f), 1e13f);
    const float C66 = fminf(fmaxf(expf(lc66[0]), 1e9f), 1e13f);
    const float r    = rho_p[0];
    const float dt2  = 2.5e-15f;
    const float kk   = dt2 * 1e6f / r;
    const float kc11 = kk * C11, kc22 = kk * C22, kc66 = kk * C66;
    const float kc16 = kk * C16, kc26 = kk * C26;
    const float kc1266 = kk * (C12 + C66);
    const float kc16x2 = 2.0f * kc16;
    const float kc26x2 = 2.0f * kc26;
    const float gsc = dt2 / r;

    // stage u_t into BOTH LDS buffers (ring cells in buf1 must be finite)
    #pragma unroll
    for (int s = 0; s < NSLOTg; ++s) {
        const int idx = tid + s * NTHRg;           // EI*EJ = 1536 = 3*512
        const int rr = idx >> 5;
        const int cc = idx & 31;
        const int gi = oi + rr, gj = oj + cc;
        const bool inbb = ((unsigned)gi < NXg) && ((unsigned)gj < NXg);
        const int go = gi * NXg + gj;
        const float vx = inbb ? gcx[go] : 0.0f;
        const float vy = inbb ? gcy[go] : 0.0f;
        sf[0][2 * idx]     = vx;  sf[0][2 * idx + 1] = vy;
        sf[1][2 * idx]     = vx;  sf[1][2 * idx + 1] = vy;
    }

    // per-slot setup
    int   la[NSLOTg], go[NSLOTg];
    float pvx[NSLOTg], pvy[NSLOTg], cvx[NSLOTg], cvy[NSLOTg], gfv[NSLOTg];
    bool  act[NSLOTg], inb[NSLOTg], own[NSLOTg];
    #pragma unroll
    for (int s = 0; s < NSLOTg; ++s) {
        const int idx = tid + s * NTHRg;
        act[s] = idx < CELg;
        const int ii = act[s] ? idx : 0;
        const int rr = ii / RCJg + 1;              // 1..46
        const int cc = ii - (rr - 1) * RCJg + 1;   // 1..30
        la[s] = ((rr << 5) + cc) * 2;
        const int gi = oi + rr, gj = oj + cc;
        inb[s] = ((unsigned)gi < NXg) && ((unsigned)gj < NXg);
        go[s] = gi * NXg + gj;
        own[s] = act[s] && rr >= Kg && rr < Kg + TIg
                        && cc >= Kg && cc < Kg + TJg;
        const bool ld = act[s] && inb[s];
        pvx[s] = ld ? gpx[go[s]] : 0.0f;
        pvy[s] = ld ? gpy[go[s]] : 0.0f;
        gfv[s] = ld ? gauss[go[s]] * gsc : 0.0f;
    }
    __syncthreads();

    // centers from LDS once; afterwards kept in registers
    #pragma unroll
    for (int s = 0; s < NSLOTg; ++s) {
        cvx[s] = sf[0][la[s]];
        cvy[s] = sf[0][la[s] + 1];
    }

    const float* cur = sf[0];
    float*       nxt = sf[1];

    #pragma unroll
    for (int st = 0; st < Kg; ++st) {
        const float fa = sig[T0 + st];
        #pragma unroll
        for (int s = 0; s < NSLOTg; ++s) {
            const int a = la[s];
            const float2 Nn = *(const float2*)&cur[a - 2 * EJg];
            const float2 Ss = *(const float2*)&cur[a + 2 * EJg];
            const float2 Ww = *(const float2*)&cur[a - 2];
            const float2 Ee = *(const float2*)&cur[a + 2];
            const float2 NW = *(const float2*)&cur[a - 2 * EJg - 2];
            const float2 NE = *(const float2*)&cur[a - 2 * EJg + 2];
            const float2 SW = *(const float2*)&cur[a + 2 * EJg - 2];
            const float2 SE = *(const float2*)&cur[a + 2 * EJg + 2];
            const float cx = cvx[s], cy = cvy[s];

            const float sxx_x = Nn.x + Ss.x - 2.0f * cx;
            const float syy_x = Ww.x + Ee.x - 2.0f * cx;
            const float sxy_x = 0.25f * (NW.x - NE.x - SW.x + SE.x);
            const float sxx_y = Nn.y + Ss.y - 2.0f * cy;
            const float syy_y = Ww.y + Ee.y - 2.0f * cy;
            const float sxy_y = 0.25f * (NW.y - NE.y - SW.y + SE.y);

            const float lux = kc11 * sxx_x + kc66 * syy_x + kc1266 * sxy_y
                            + kc16x2 * sxy_x + kc16 * sxx_y + kc26 * syy_y;
            const float luy = kc66 * sxx_y + kc22 * syy_y + kc1266 * sxy_x
                            + kc16 * sxx_x + kc26 * syy_x + kc26x2 * sxy_y
                            + fa * gfv[s];

            float vx = 2.0f * cx - pvx[s] + lux;
            float vy = 2.0f * cy - pvy[s] + luy;
            vx = inb[s] ? vx : 0.0f;     // zero outside domain (matches padding)
            vy = inb[s] ? vy : 0.0f;
            pvx[s] = cx;  pvy[s] = cy;
            cvx[s] = vx;  cvy[s] = vy;

            if (act[s]) {
                nxt[a]     = vx;
                nxt[a + 1] = vy;
            }
            if ((st & 3) == 0) {         // compile-time: st = 0, 4
                if (own[s]) {
                    const int fo = ((T0 + st) >> 2) * Sg + go[s];
                    out[fo] = vx;
                    out[fo + NFRg * Sg] = vy;
                }
            }
        }
        __syncthreads();
        float* tmp = (float*)cur; cur = nxt; nxt = tmp;
    }

    // handoff from registers (each owned cell written by exactly one block)
    #pragma unroll
    for (int s = 0; s < NSLOTg; ++s) {
        if (own[s]) {
            ncx[go[s]] = cvx[s];
            ncy[go[s]] = cvy[s];
            npx[go[s]] = pvx[s];
            npy[go[s]] = pvy[s];
        }
    }
}

extern "C" void kernel_launch(void* const* d_in, const int* in_sizes, int n_in,
                              void* d_out, int out_size, void* d_ws, size_t ws_size,
                              hipStream_t stream) {
    const float* lc11  = (const float*)d_in[0];
    const float* lc22  = (const float*)d_in[1];
    const float* lc12  = (const float*)d_in[2];
    const float* lc16  = (const float*)d_in[3];
    const float* lc26  = (const float*)d_in[4];
    const float* lc66  = (const float*)d_in[5];
    const float* rho_p = (const float*)d_in[6];
    const float* sig   = (const float*)d_in[7];
    const float* gauss = (const float*)d_in[8];
    float* out = (float*)d_out;
    float* ws  = (float*)d_ws;

    float* A[4] = { ws,          ws + Sg,     ws + 2 * Sg, ws + 3 * Sg };
    float* B[4] = { ws + 4 * Sg, ws + 5 * Sg, ws + 6 * Sg, ws + 7 * Sg };

    hipLaunchKernelGGL(cfrp_init, dim3(Sg / NTHRg), dim3(NTHRg), 0, stream, ws);

    for (int c = 0; c < NCHUNK; ++c) {
        float** R = (c & 1) ? B : A;
        float** W = (c & 1) ? A : B;
        hipLaunchKernelGGL(cfrp_chunk, dim3(512), dim3(NTHRg), 0, stream,
                           lc11, lc22, lc12, lc16, lc26, lc66, rho_p, sig,
                           gauss, out,
                           R[0], R[1], R[2], R[3],
                           W[0], W[1], W[2], W[3],
                           c * Kg);
    }
}

// Round 6
// 663.802 us; speedup vs baseline: 11.8992x; 1.0157x over previous
//
#include <hip/hip_runtime.h>

// ---- problem constants ----
#define NXg    512
#define Sg     262144          // 512*512
#define NFRg   60
// ---- temporal blocking ----
#define Kg     8               // steps per chunk
#define NCHUNK 30              // 240 / 8
#define Tg     16              // owned tile dim (16x16)
#define Eg     32              // extended tile dim (T + 2K)
#define RCg    30              // compute region 1..30
#define CELg   900             // 30*30 compute cells
#define NTB    1024            // threads per block (one slot: 900 active)

// Zero the A-set state (cur2 + prev2 = 2*Sg float2). B-set is fully
// overwritten by chunk 0 before being read. ws re-poisoned 0xAA every call.
__global__ __launch_bounds__(512)
void cfrp_init(float2* __restrict__ ws2)
{
    const int gt = (int)blockIdx.x * 512 + (int)threadIdx.x;  // 524288 = 2*Sg
    ws2[gt] = make_float2(0.f, 0.f);
}

// Advance 8 timesteps. One lane = one compute cell (no slot loop).
// State float2-interleaved {ux,uy}; LDS double-buffered, 1 barrier/step.
// Center + u_{t-1} live in registers.
__global__ __launch_bounds__(NTB, 8)
void cfrp_chunk(const float* __restrict__ lc11, const float* __restrict__ lc22,
                const float* __restrict__ lc12, const float* __restrict__ lc16,
                const float* __restrict__ lc26, const float* __restrict__ lc66,
                const float* __restrict__ rho_p, const float* __restrict__ sig,
                const float* __restrict__ gauss, float* __restrict__ out,
                const float2* __restrict__ gcur, const float2* __restrict__ gprev,
                float2* __restrict__ ncur, float2* __restrict__ nprev,
                int T0)
{
    __shared__ float2 sf[2][Eg * Eg];

    const int tid = (int)threadIdx.x;
    // XCD-affinity swizzle (heuristic: wg -> XCD = wg & 7 round-robin).
    // XCD q owns tile-band rows 4q..4q+3, all 32 tile-cols: its 64x512-cell
    // state slice stays in the same XCD L2 across all 30 chunks.
    const int w  = (int)blockIdx.x;
    const int q  = w & 7;
    const int r_ = w >> 3;                 // 0..127 within XCD
    const int ti = q * 4 + (r_ >> 5);      // tile row 0..31
    const int tj = r_ & 31;                // tile col 0..31
    const int oi = ti * Tg - Kg;
    const int oj = tj * Tg - Kg;

    // uniform material constants
    const float C11 = fminf(fmaxf(expf(lc11[0]), 1e9f), 1e13f);
    const float C22 = fminf(fmaxf(expf(lc22[0]), 1e9f), 1e13f);
    const float C12 = fminf(fmaxf(expf(lc12[0]), 1e9f), 1e13f);
    const float C16 = fminf(fmaxf(expf(lc16[0]), 1e9f), 1e13f);
    const float C26 = fminf(fmaxf(expf(lc26[0]), 1e9f), 1e13f);
    const float C66 = fminf(fmaxf(expf(lc66[0]), 1e9f), 1e13f);
    const float r    = rho_p[0];
    const float dt2  = 2.5e-15f;
    const float kk   = dt2 * 1e6f / r;
    const float kc11 = kk * C11, kc22 = kk * C22, kc66 = kk * C66;
    const float kc16 = kk * C16, kc26 = kk * C26;
    const float kc1266 = kk * (C12 + C66);
    const float kc16x2 = 2.0f * kc16;
    const float kc26x2 = 2.0f * kc26;
    const float gsc = dt2 / r;

    // stage u_t into both LDS buffers (1024 threads = 1024 ext cells)
    {
        const int rr = tid >> 5, cc = tid & 31;
        const int gi = oi + rr, gj = oj + cc;
        const bool inbb = ((unsigned)gi < NXg) && ((unsigned)gj < NXg);
        float2 v = make_float2(0.f, 0.f);
        if (inbb) v = gcur[gi * NXg + gj];
        sf[0][tid] = v;
        sf[1][tid] = v;
    }

    // per-lane cell setup (lanes >= CELg clamp to cell 899: benign dupes)
    const bool activ = tid < CELg;
    const int  ii = activ ? tid : (CELg - 1);
    const int  rr = ii / RCg + 1;              // 1..30
    const int  cc = ii - (rr - 1) * RCg + 1;   // 1..30
    const int  la = (rr << 5) + cc;
    const int  gi = oi + rr, gj = oj + cc;
    const bool inb = ((unsigned)gi < NXg) && ((unsigned)gj < NXg);
    const int  go = gi * NXg + gj;
    const bool own = activ && rr >= Kg && rr < Kg + Tg
                           && cc >= Kg && cc < Kg + Tg;
    float2 pv = make_float2(0.f, 0.f);
    float  gf = 0.f;
    if (inb) {
        pv = gprev[go];
        gf = gauss[go] * gsc;
    }
    __syncthreads();

    float2 cv = sf[0][la];                     // center in registers

    const float2* cur = sf[0];
    float2*       nxt = sf[1];

    #pragma unroll
    for (int st = 0; st < Kg; ++st) {
        const float fa = sig[T0 + st];
        const float2 Nn = cur[la - Eg];
        const float2 Ss = cur[la + Eg];
        const float2 Ww = cur[la - 1];
        const float2 Ee = cur[la + 1];
        const float2 NW = cur[la - Eg - 1];
        const float2 NE = cur[la - Eg + 1];
        const float2 SW = cur[la + Eg - 1];
        const float2 SE = cur[la + Eg + 1];
        const float cx = cv.x, cy = cv.y;

        const float sxx_x = Nn.x + Ss.x - 2.0f * cx;
        const float syy_x = Ww.x + Ee.x - 2.0f * cx;
        const float sxy_x = 0.25f * (NW.x - NE.x - SW.x + SE.x);
        const float sxx_y = Nn.y + Ss.y - 2.0f * cy;
        const float syy_y = Ww.y + Ee.y - 2.0f * cy;
        const float sxy_y = 0.25f * (NW.y - NE.y - SW.y + SE.y);

        const float lux = kc11 * sxx_x + kc66 * syy_x + kc1266 * sxy_y
                        + kc16x2 * sxy_x + kc16 * sxx_y + kc26 * syy_y;
        const float luy = kc66 * sxx_y + kc22 * syy_y + kc1266 * sxy_x
                        + kc16 * sxx_x + kc26 * syy_x + kc26x2 * sxy_y
                        + fa * gf;

        float vx = 2.0f * cx - pv.x + lux;
        float vy = 2.0f * cy - pv.y + luy;
        vx = inb ? vx : 0.0f;       // out-of-domain cells stay 0 (zero padding)
        vy = inb ? vy : 0.0f;
        pv = cv;
        cv = make_float2(vx, vy);

        nxt[la] = cv;

        if ((st & 3) == 0) {        // compile-time: st = 0, 4
            if (own) {
                const int fo = ((T0 + st) >> 2) * Sg + go;
                out[fo] = vx;
                out[fo + NFRg * Sg] = vy;
            }
        }
        __syncthreads();
        float2* tmp = (float2*)cur; cur = nxt; nxt = tmp;
    }

    // handoff from registers (each owned cell written by exactly one block)
    if (own) {
        ncur[go]  = cv;
        nprev[go] = pv;
    }
}

extern "C" void kernel_launch(void* const* d_in, const int* in_sizes, int n_in,
                              void* d_out, int out_size, void* d_ws, size_t ws_size,
                              hipStream_t stream) {
    const float* lc11  = (const float*)d_in[0];
    const float* lc22  = (const float*)d_in[1];
    const float* lc12  = (const float*)d_in[2];
    const float* lc16  = (const float*)d_in[3];
    const float* lc26  = (const float*)d_in[4];
    const float* lc66  = (const float*)d_in[5];
    const float* rho_p = (const float*)d_in[6];
    const float* sig   = (const float*)d_in[7];
    const float* gauss = (const float*)d_in[8];
    float* out = (float*)d_out;
    float2* ws2 = (float2*)d_ws;

    // A-set: [cur, prev], B-set: [cur, prev] (float2 each, Sg elements)
    float2* Ac = ws2;           float2* Ap = ws2 + Sg;
    float2* Bc = ws2 + 2 * Sg;  float2* Bp = ws2 + 3 * Sg;

    hipLaunchKernelGGL(cfrp_init, dim3(2 * Sg / 512), dim3(512), 0, stream, ws2);

    for (int c = 0; c < NCHUNK; ++c) {
        float2 *rc, *rp, *wc, *wp;
        if (c & 1) { rc = Bc; rp = Bp; wc = Ac; wp = Ap; }
        else       { rc = Ac; rp = Ap; wc = Bc; wp = Bp; }
        hipLaunchKernelGGL(cfrp_chunk, dim3(1024), dim3(NTB), 0, stream,
                           lc11, lc22, lc12, lc16, lc26, lc66, rho_p, sig,
                           gauss, out, rc, rp, wc, wp, c * Kg);
    }
}

// Round 7
// 547.984 us; speedup vs baseline: 14.4141x; 1.2114x over previous
//
#include <hip/hip_runtime.h>

// ---- problem constants ----
#define NXg    512
#define Sg     262144          // 512*512
#define NFRg   60
// ---- temporal blocking ----
#define Kg     8               // steps per chunk
#define NCHUNK 30              // 240 / 8
#define Tg     32              // owned tile (32x32), 16x16 tiles = 256 blocks
#define Eg     48              // extended tile (T + 2K)
#define EJP    50              // padded LDS row stride in float2 (400 B)
#define NSEGR  12              // 4-cell segments per row
#define NTHR   576             // 48 rows * 12 segments = 9 waves

// Zero the A-set state (cur+prev interleaved float2 = Sg float4 total).
// B-set is fully overwritten by chunk 0 before being read.
__global__ __launch_bounds__(512)
void cfrp_init(float4* __restrict__ ws4)
{
    const int gt = (int)blockIdx.x * 512 + (int)threadIdx.x;  // 262144
    ws4[gt] = make_float4(0.f, 0.f, 0.f, 0.f);
}

// Advance 8 timesteps. Each thread owns a 1x4 horizontal cell strip.
// LDS: float2 {ux,uy} per cell, rows padded to 50 float2; double-buffered,
// one barrier per step. Strip centers + u_{t-1} live in registers; E/W
// neighbors inside the strip come from registers.
__global__ __launch_bounds__(NTHR)
void cfrp_chunk(const float* __restrict__ lc11, const float* __restrict__ lc22,
                const float* __restrict__ lc12, const float* __restrict__ lc16,
                const float* __restrict__ lc26, const float* __restrict__ lc66,
                const float* __restrict__ rho_p, const float* __restrict__ sig,
                const float* __restrict__ gauss, float* __restrict__ out,
                const float2* __restrict__ gcur, const float2* __restrict__ gprev,
                float2* __restrict__ ncur, float2* __restrict__ nprev,
                int TB)
{
    __shared__ float2 sf[2][Eg * EJP];

    const int tid = (int)threadIdx.x;
    // XCD-affinity: XCD q (= wg&7 round-robin) owns tile-rows 2q..2q+1.
    const int w  = (int)blockIdx.x;
    const int q  = w & 7;
    const int r_ = w >> 3;                 // 0..31
    const int ti = q * 2 + (r_ >> 4);      // 0..15
    const int tj = r_ & 15;                // 0..15
    const int oi = ti * Tg - Kg;
    const int oj = tj * Tg - Kg;

    // uniform material constants
    const float C11 = fminf(fmaxf(expf(lc11[0]), 1e9f), 1e13f);
    const float C22 = fminf(fmaxf(expf(lc22[0]), 1e9f), 1e13f);
    const float C12 = fminf(fmaxf(expf(lc12[0]), 1e9f), 1e13f);
    const float C16 = fminf(fmaxf(expf(lc16[0]), 1e9f), 1e13f);
    const float C26 = fminf(fmaxf(expf(lc26[0]), 1e9f), 1e13f);
    const float C66 = fminf(fmaxf(expf(lc66[0]), 1e9f), 1e13f);
    const float rh   = rho_p[0];
    const float dt2  = 2.5e-15f;
    const float kk   = dt2 * 1e6f / rh;
    const float kc11 = kk * C11, kc22 = kk * C22, kc66 = kk * C66;
    const float kc16 = kk * C16, kc26 = kk * C26;
    const float kc1266 = kk * (C12 + C66);
    const float kc16x2 = 2.0f * kc16;
    const float kc26x2 = 2.0f * kc26;
    const float gsc = dt2 / rh;

    // ---- stage u_t into both LDS buffers (float4 = 2 cells, coalesced) ----
    #pragma unroll
    for (int s = 0; s < 2; ++s) {
        const int p  = tid + s * NTHR;       // 0..1151 (= 48*24 cell pairs)
        const int rr = p / 24;
        const int cp = (p - rr * 24) * 2;    // even ext col
        const int gi = oi + rr;
        const int gj = oj + cp;              // even
        float4 v = make_float4(0.f, 0.f, 0.f, 0.f);
        if (((unsigned)gi < NXg) && ((unsigned)gj < NXg))
            v = *(const float4*)&gcur[gi * NXg + gj];
        const int li = rr * EJP + cp;
        *(float4*)&sf[0][li] = v;
        *(float4*)&sf[1][li] = v;
    }
    // zero the 2-float2 pad of every row (keeps all LDS reads finite)
    if (tid < Eg) {
        const int li = tid * EJP + Eg;
        *(float4*)&sf[0][li] = make_float4(0.f, 0.f, 0.f, 0.f);
        *(float4*)&sf[1][li] = make_float4(0.f, 0.f, 0.f, 0.f);
    }

    // ---- per-segment setup ----
    const int  srow = tid / NSEGR;
    const int  scol = tid - srow * NSEGR;
    const bool act  = (srow >= 1) && (srow <= Eg - 2);
    const int  c0   = scol * 4;              // ext col of strip cell 0
    const int  gi   = oi + srow;
    const int  gj0  = oj + c0;               // multiple of 4
    const int  idxC = srow * EJP + c0;
    const bool rin  = (unsigned)gi < NXg;
    bool inb0 = rin && ((unsigned)(gj0 + 0) < NXg);
    bool inb1 = rin && ((unsigned)(gj0 + 1) < NXg);
    bool inb2 = rin && ((unsigned)(gj0 + 2) < NXg);
    bool inb3 = rin && ((unsigned)(gj0 + 3) < NXg);
    const bool own = (srow >= Kg) && (srow < Kg + Tg) && (scol >= 2) && (scol <= 9);
    const int  go0 = gi * NXg + gj0;

    float2 pv0 = {0.f,0.f}, pv1 = {0.f,0.f}, pv2 = {0.f,0.f}, pv3 = {0.f,0.f};
    float  gf0 = 0.f, gf1 = 0.f, gf2 = 0.f, gf3 = 0.f;
    if (act && rin) {
        if ((unsigned)gj0 < NXg) {
            const float4 t = *(const float4*)&gprev[go0];
            pv0 = make_float2(t.x, t.y); pv1 = make_float2(t.z, t.w);
            const float4 g = *(const float4*)&gauss[go0];   // 4 cells, aligned
            gf0 = g.x * gsc; gf1 = g.y * gsc; gf2 = g.z * gsc; gf3 = g.w * gsc;
        }
        if ((unsigned)(gj0 + 2) < NXg) {
            const float4 t = *(const float4*)&gprev[go0 + 2];
            pv2 = make_float2(t.x, t.y); pv3 = make_float2(t.z, t.w);
        }
    }
    __syncthreads();

    // strip centers into registers
    float2 cv0, cv1, cv2, cv3;
    {
        const float4 a = *(const float4*)&sf[0][idxC];
        const float4 b = *(const float4*)&sf[0][idxC + 2];
        cv0 = make_float2(a.x, a.y); cv1 = make_float2(a.z, a.w);
        cv2 = make_float2(b.x, b.y); cv3 = make_float2(b.z, b.w);
    }

    const float2* cur = sf[0];
    float2*       nxt = sf[1];

    #pragma unroll
    for (int st = 0; st < Kg; ++st) {
        const float fa = sig[TB + st];
        if (act) {
            const int iT = idxC - EJP;
            const int iB = idxC + EJP;
            const float4 t01 = *(const float4*)&cur[iT];
            const float4 t23 = *(const float4*)&cur[iT + 2];
            const float2 twv = cur[iT - 1];
            const float2 tev = cur[iT + 4];
            const float4 b01 = *(const float4*)&cur[iB];
            const float4 b23 = *(const float4*)&cur[iB + 2];
            const float2 bwv = cur[iB - 1];
            const float2 bev = cur[iB + 4];
            const float2 wmv = cur[idxC - 1];
            const float2 emv = cur[idxC + 4];

            const float2 ta0 = twv, ta1 = make_float2(t01.x, t01.y),
                         ta2 = make_float2(t01.z, t01.w),
                         ta3 = make_float2(t23.x, t23.y),
                         ta4 = make_float2(t23.z, t23.w), ta5 = tev;
            const float2 ba0 = bwv, ba1 = make_float2(b01.x, b01.y),
                         ba2 = make_float2(b01.z, b01.w),
                         ba3 = make_float2(b23.x, b23.y),
                         ba4 = make_float2(b23.z, b23.w), ba5 = bev;

            float2 nv0, nv1, nv2, nv3;
            #define CELLSTEP(nv, NW, N, NE, Wt, C, Et, SW, S, SE, P, GF, INB)   \
            {                                                                    \
                const float sxx_x = N.x + S.x - 2.0f * C.x;                      \
                const float syy_x = Wt.x + Et.x - 2.0f * C.x;                    \
                const float sxy_x = 0.25f * (NW.x - NE.x - SW.x + SE.x);         \
                const float sxx_y = N.y + S.y - 2.0f * C.y;                      \
                const float syy_y = Wt.y + Et.y - 2.0f * C.y;                    \
                const float sxy_y = 0.25f * (NW.y - NE.y - SW.y + SE.y);         \
                const float lux = kc11 * sxx_x + kc66 * syy_x + kc1266 * sxy_y   \
                                + kc16x2 * sxy_x + kc16 * sxx_y + kc26 * syy_y;  \
                const float luy = kc66 * sxx_y + kc22 * syy_y + kc1266 * sxy_x   \
                                + kc16 * sxx_x + kc26 * syy_x + kc26x2 * sxy_y   \
                                + fa * GF;                                       \
                float vx = 2.0f * C.x - P.x + lux;                               \
                float vy = 2.0f * C.y - P.y + luy;                               \
                vx = INB ? vx : 0.0f;                                            \
                vy = INB ? vy : 0.0f;                                            \
                nv = make_float2(vx, vy);                                        \
            }
            CELLSTEP(nv0, ta0, ta1, ta2, wmv, cv0, cv1, ba0, ba1, ba2, pv0, gf0, inb0)
            CELLSTEP(nv1, ta1, ta2, ta3, cv0, cv1, cv2, ba1, ba2, ba3, pv1, gf1, inb1)
            CELLSTEP(nv2, ta2, ta3, ta4, cv1, cv2, cv3, ba2, ba3, ba4, pv2, gf2, inb2)
            CELLSTEP(nv3, ta3, ta4, ta5, cv2, cv3, emv, ba3, ba4, ba5, pv3, gf3, inb3)
            #undef CELLSTEP

            pv0 = cv0; pv1 = cv1; pv2 = cv2; pv3 = cv3;
            cv0 = nv0; cv1 = nv1; cv2 = nv2; cv3 = nv3;

            *(float4*)&nxt[idxC]     = make_float4(cv0.x, cv0.y, cv1.x, cv1.y);
            *(float4*)&nxt[idxC + 2] = make_float4(cv2.x, cv2.y, cv3.x, cv3.y);

            if (((st & 3) == 0) && own) {          // st = 0, 4 (compile-time)
                const int fr = (TB + st) >> 2;
                *(float4*)&out[fr * Sg + go0] =
                    make_float4(cv0.x, cv1.x, cv2.x, cv3.x);
                *(float4*)&out[(fr + NFRg) * Sg + go0] =
                    make_float4(cv0.y, cv1.y, cv2.y, cv3.y);
            }
        }
        __syncthreads();
        float2* tmp = (float2*)cur; cur = nxt; nxt = tmp;
    }

    // handoff from registers (owned cells: rows 8..39, cols 8..39 of ext)
    if (own) {
        *(float4*)&ncur[go0]      = make_float4(cv0.x, cv0.y, cv1.x, cv1.y);
        *(float4*)&ncur[go0 + 2]  = make_float4(cv2.x, cv2.y, cv3.x, cv3.y);
        *(float4*)&nprev[go0]     = make_float4(pv0.x, pv0.y, pv1.x, pv1.y);
        *(float4*)&nprev[go0 + 2] = make_float4(pv2.x, pv2.y, pv3.x, pv3.y);
    }
}

extern "C" void kernel_launch(void* const* d_in, const int* in_sizes, int n_in,
                              void* d_out, int out_size, void* d_ws, size_t ws_size,
                              hipStream_t stream) {
    const float* lc11  = (const float*)d_in[0];
    const float* lc22  = (const float*)d_in[1];
    const float* lc12  = (const float*)d_in[2];
    const float* lc16  = (const float*)d_in[3];
    const float* lc26  = (const float*)d_in[4];
    const float* lc66  = (const float*)d_in[5];
    const float* rho_p = (const float*)d_in[6];
    const float* sig   = (const float*)d_in[7];
    const float* gauss = (const float*)d_in[8];
    float* out  = (float*)d_out;
    float2* ws2 = (float2*)d_ws;

    float2* Ac = ws2;           float2* Ap = ws2 + Sg;
    float2* Bc = ws2 + 2 * Sg;  float2* Bp = ws2 + 3 * Sg;

    hipLaunchKernelGGL(cfrp_init, dim3(512), dim3(512), 0, stream, (float4*)d_ws);

    for (int c = 0; c < NCHUNK; ++c) {
        float2 *rc, *rp, *wc, *wp;
        if (c & 1) { rc = Bc; rp = Bp; wc = Ac; wp = Ap; }
        else       { rc = Ac; rp = Ap; wc = Bc; wp = Bp; }
        hipLaunchKernelGGL(cfrp_chunk, dim3(256), dim3(NTHR), 0, stream,
                           lc11, lc22, lc12, lc16, lc26, lc66, rho_p, sig,
                           gauss, out, rc, rp, wc, wp, c * Kg);
    }
}